// Round 11
// baseline (178.326 us; speedup 1.0000x reference)
//
#include <hip/hip_runtime.h>
#include <stdint.h>

#define N_TOK 4096
#define DIM   512
#define BATCH 4
#define BN    (BATCH * N_TOK)
#define NTILE 16                      // 256-row tiles per batch
#define NPAIR (NTILE * (NTILE + 1) / 2)   // 136 upper-triangle tile-pairs
#define IPW   64                      // i-rows per wave (A resident in regs)
#define IPB   256                     // i-rows per block (4 waves)
#define NG    16                      // j-groups of 16 per 256-wide tile

typedef __attribute__((ext_vector_type(4))) float f32x4;

__device__ __forceinline__ float sumsq8(uint lo, uint hi) {
    float s = 0.f, f;
    f = __builtin_amdgcn_cvt_f32_fp8((int)lo, 0); s = fmaf(f, f, s);
    f = __builtin_amdgcn_cvt_f32_fp8((int)lo, 1); s = fmaf(f, f, s);
    f = __builtin_amdgcn_cvt_f32_fp8((int)lo, 2); s = fmaf(f, f, s);
    f = __builtin_amdgcn_cvt_f32_fp8((int)lo, 3); s = fmaf(f, f, s);
    f = __builtin_amdgcn_cvt_f32_fp8((int)hi, 0); s = fmaf(f, f, s);
    f = __builtin_amdgcn_cvt_f32_fp8((int)hi, 1); s = fmaf(f, f, s);
    f = __builtin_amdgcn_cvt_f32_fp8((int)hi, 2); s = fmaf(f, f, s);
    f = __builtin_amdgcn_cvt_f32_fp8((int)hi, 3); s = fmaf(f, f, s);
    return s;
}

// ---------- prep: fp8 convert -> fb (row-major) + fbT (B-operand, 16B-load layout)
//            + per-row sumsq of QUANTIZED values (diag d_ii ~ 0 matches ref k_ii=1).
// fbT per 16-row group (8KB): long index p = kp*128 + q*32 + r16*2 + half.
__global__ __launch_bounds__(256) void prep_kernel(
    const float* __restrict__ feat, uint8_t* __restrict__ fb,
    uint8_t* __restrict__ fbT, float* __restrict__ sq)
{
    __shared__ __align__(16) long lt[1024];        // [chunk c 0..63][row16], swizzled
    const int t = threadIdx.x;
    const int row16 = t >> 4, seg = t & 15;
    const size_t grp = blockIdx.x;
    const size_t row = grp * 16 + row16;

    const float4* src = (const float4*)(feat + row * DIM + seg * 32);
    uint32_t wd[8];
    float s = 0.f;
#pragma unroll
    for (int i = 0; i < 4; ++i) {
        float4 a = src[2 * i], b = src[2 * i + 1];
        uint lo = (uint)__builtin_amdgcn_cvt_pk_fp8_f32(a.x, a.y, 0, false);
        lo      = (uint)__builtin_amdgcn_cvt_pk_fp8_f32(a.z, a.w, (int)lo, true);
        uint hi = (uint)__builtin_amdgcn_cvt_pk_fp8_f32(b.x, b.y, 0, false);
        hi      = (uint)__builtin_amdgcn_cvt_pk_fp8_f32(b.z, b.w, (int)hi, true);
        wd[2 * i] = lo; wd[2 * i + 1] = hi;
        s += sumsq8(lo, hi);
    }

    uint4* dst = (uint4*)(fb + row * DIM + seg * 32);
    uint4 o0; o0.x = wd[0]; o0.y = wd[1]; o0.z = wd[2]; o0.w = wd[3];
    uint4 o1; o1.x = wd[4]; o1.y = wd[5]; o1.z = wd[6]; o1.w = wd[7];
    dst[0] = o0; dst[1] = o1;

#pragma unroll
    for (int i = 0; i < 4; ++i) {
        int c = seg * 4 + i;                       // 8B chunk of this row
        long d = ((long)(unsigned)wd[2 * i + 1] << 32) | (unsigned)wd[2 * i];
        lt[c * 16 + ((row16 + c) & 15)] = d;
    }

#pragma unroll
    for (int m = 1; m < 16; m <<= 1) s += __shfl_xor(s, m);
    if (seg == 0) sq[row] = s;

    __syncthreads();
    long* ot = (long*)(fbT + grp * 8192);
#pragma unroll
    for (int i = 0; i < 4; ++i) {
        int p    = t + i * 256;                    // output long index, coalesced
        int kp   = p >> 7;
        int q    = (p >> 5) & 3;
        int r    = (p >> 1) & 15;
        int half = p & 1;
        int c    = (((kp << 1) | half) << 2) | q;  // source chunk
        ot[p] = lt[c * 16 + ((r + c) & 15)];
    }
}

// ---------- entropy: SYMMETRIC upper-triangle tile-pairs ----------
// k_ij == k_ji exactly (same quantized operands), so grid (136,B) covers pairs
// (ti<=tj) of 256x256 tiles: row-sums (c16-reduce) go to i-rows; for ti<tj the
// col-sums (reg+quad reduce) additionally go to j-rows. Col path lives inside the
// exp-skip branch => fires only near the diagonal => atomic traffic ~0.
// Halves MFMA work and B-traffic vs the full grid (136/256).
__global__ __launch_bounds__(256, 2) void entropy_kernel(
    const uint8_t* __restrict__ fb, const uint8_t* __restrict__ fbT,
    const float* __restrict__ sq, const float* __restrict__ temp,
    float* __restrict__ Sp, float* __restrict__ Tp)
{
    const int t    = threadIdx.x;
    const int w    = t >> 6;
    const int lane = t & 63;
    const int q    = lane >> 4;
    const int c16  = lane & 15;

    int ti = 0, rem = blockIdx.x;                  // decode pair -> (ti <= tj)
    while (rem >= NTILE - ti) { rem -= NTILE - ti; ++ti; }
    const int  tj   = ti + rem;
    const bool diag = (ti == tj);

    const int batch = blockIdx.y;
    const int iw    = ti * IPB + w * IPW;
    const size_t rowbase = (size_t)batch * N_TOK;

    const float tau    = temp[0];
    const float inv2t2 = 0.5f / (tau * tau);
    const float cg     = 1.0f / (tau * tau);

    // A fragments: 4 strips x 16 k-chunks x 8B = 128 regs
    long afrag[4][16];
#pragma unroll
    for (int s = 0; s < 4; ++s) {
        const long* ap = (const long*)(fb + (rowbase + iw + s * 16 + c16) * DIM);
#pragma unroll
        for (int kc = 0; kc < 16; ++kc) afrag[s][kc] = ap[kc * 4 + q];
    }
    float pi[4][4];
#pragma unroll
    for (int s = 0; s < 4; ++s)
#pragma unroll
        for (int r = 0; r < 4; ++r)
            pi[s][r] = -sq[rowbase + iw + s * 16 + q * 4 + r] * inv2t2;

    float S[4][4], T[4][4];
#pragma unroll
    for (int s = 0; s < 4; ++s)
#pragma unroll
        for (int r = 0; r < 4; ++r) { S[s][r] = 0.f; T[s][r] = 0.f; }

    // per-lane B pointer into tj's 16 groups (16B units, kp stride 64 units)
    const longlong2* bp = (const longlong2*)(fbT
                        + ((size_t)batch * (N_TOK / 16) + (size_t)tj * NG) * 8192) + lane;
    const float* sqj = sq + rowbase + tj * IPB + c16;

    for (int g = 0; g < NG; ++g) {
        float pj = -sqj[g * 16] * inv2t2;
        const longlong2* bg = bp + (size_t)g * 512;
        f32x4 acc[4] = {{0,0,0,0},{0,0,0,0},{0,0,0,0},{0,0,0,0}};
#pragma unroll
        for (int kp = 0; kp < 8; ++kp) {
            longlong2 v = bg[kp * 64];             // coalesced 1KB wave load, 2 kc
            acc[0] = __builtin_amdgcn_mfma_f32_16x16x32_fp8_fp8(afrag[0][2*kp],   v.x, acc[0], 0, 0, 0);
            acc[1] = __builtin_amdgcn_mfma_f32_16x16x32_fp8_fp8(afrag[1][2*kp],   v.x, acc[1], 0, 0, 0);
            acc[2] = __builtin_amdgcn_mfma_f32_16x16x32_fp8_fp8(afrag[2][2*kp],   v.x, acc[2], 0, 0, 0);
            acc[3] = __builtin_amdgcn_mfma_f32_16x16x32_fp8_fp8(afrag[3][2*kp],   v.x, acc[3], 0, 0, 0);
            acc[0] = __builtin_amdgcn_mfma_f32_16x16x32_fp8_fp8(afrag[0][2*kp+1], v.y, acc[0], 0, 0, 0);
            acc[1] = __builtin_amdgcn_mfma_f32_16x16x32_fp8_fp8(afrag[1][2*kp+1], v.y, acc[1], 0, 0, 0);
            acc[2] = __builtin_amdgcn_mfma_f32_16x16x32_fp8_fp8(afrag[2][2*kp+1], v.y, acc[2], 0, 0, 0);
            acc[3] = __builtin_amdgcn_mfma_f32_16x16x32_fp8_fp8(afrag[3][2*kp+1], v.y, acc[3], 0, 0, 0);
        }
        float m = -1e30f;
#pragma unroll
        for (int s = 0; s < 4; ++s)
#pragma unroll
            for (int r = 0; r < 4; ++r) {          // e in place of acc (dead after)
                acc[s][r] = fmaf(acc[s][r], cg, pi[s][r] + pj);
                m = fmaxf(m, acc[s][r]);
            }
        if (m > -110.0f) {                         // only diagonal-adjacent groups
            float cs = 0.f, ct = 0.f;
#pragma unroll
            for (int s = 0; s < 4; ++s)
#pragma unroll
                for (int r = 0; r < 4; ++r) {
                    float ee = fminf(acc[s][r], 0.f);
                    float k  = __expf(ee);
                    S[s][r] += k;  T[s][r] = fmaf(k, ee, T[s][r]);
                    cs      += k;  ct      = fmaf(k, ee, ct);
                }
            if (!diag) {                           // col-sums -> j-rows (k symmetric)
                cs += __shfl_xor(cs, 16); cs += __shfl_xor(cs, 32);
                ct += __shfl_xor(ct, 16); ct += __shfl_xor(ct, 32);
                if (q == 0) {
                    size_t jrow = rowbase + (size_t)tj * IPB + g * 16 + c16;
                    atomicAdd(&Sp[jrow], cs);
                    atomicAdd(&Tp[jrow], ct);
                }
            }
        }
    }

    // row-sums: reduce over the 16 j-columns, then atomic-accumulate to i-rows
#pragma unroll
    for (int m = 1; m < 16; m <<= 1)
#pragma unroll
        for (int s = 0; s < 4; ++s)
#pragma unroll
            for (int r = 0; r < 4; ++r) {
                S[s][r] += __shfl_xor(S[s][r], m);
                T[s][r] += __shfl_xor(T[s][r], m);
            }
    if (c16 == 0) {
#pragma unroll
        for (int s = 0; s < 4; ++s)
#pragma unroll
            for (int r = 0; r < 4; ++r) {
                size_t idx = rowbase + iw + s * 16 + q * 4 + r;
                atomicAdd(&Sp[idx], S[s][r]);
                atomicAdd(&Tp[idx], T[s][r]);
            }
    }
}

// ---------- finalize: entropy -> sigmoid -> scale features ----------
__global__ __launch_bounds__(256) void finalize_kernel(
    const float* __restrict__ feat, const float* __restrict__ Sp,
    const float* __restrict__ Tp, const float* __restrict__ tgt,
    const float* __restrict__ temp, float* __restrict__ out)
{
    int row  = (blockIdx.x << 2) + (threadIdx.x >> 6);   // global row 0..BN-1
    int lane = threadIdx.x & 63;
    float S = Sp[row], T = Tp[row];
    float tau = temp[0];
    float E  = __logf(S) - T / S;                  // entropy (sans +1e-6, bias<4e-3)
    float cs = 1.0f / (1.0f + __expf((E - tgt[0]) / tau));

    const float4* F4 = (const float4*)(feat + (size_t)row * DIM);
    float4*       O4 = (float4*)(out + (size_t)row * DIM);
    float4 v0 = F4[lane], v1 = F4[lane + 64];
    v0.x *= cs; v0.y *= cs; v0.z *= cs; v0.w *= cs;
    v1.x *= cs; v1.y *= cs; v1.z *= cs; v1.w *= cs;
    O4[lane] = v0; O4[lane + 64] = v1;
    if (lane == 0) out[(size_t)BN * DIM + row] = cs;
}

extern "C" void kernel_launch(void* const* d_in, const int* in_sizes, int n_in,
                              void* d_out, int out_size, void* d_ws, size_t ws_size,
                              hipStream_t stream) {
    const float* feat = (const float*)d_in[0];
    const float* tgt  = (const float*)d_in[7];   // target_entropy
    const float* temp = (const float*)d_in[8];   // temperature
    float* out = (float*)d_out;

    char* ws = (char*)d_ws;
    uint8_t* fb  = (uint8_t*)ws;                               // fp8 row-major, 8.4MB
    uint8_t* fbT = fb + (size_t)BN * DIM;                      // fp8 B-layout, 8.4MB
    float*   sq  = (float*)(fbT + (size_t)BN * DIM);           // quantized row sumsq
    float*   Sp  = sq + BN;                                    // S accumulators (atomic)
    float*   Tp  = Sp + BN;                                    // T accumulators (atomic)

    hipMemsetAsync(Sp, 0, 2 * (size_t)BN * sizeof(float), stream);
    prep_kernel<<<dim3(BN / 16), dim3(256), 0, stream>>>(feat, fb, fbT, sq);
    entropy_kernel<<<dim3(NPAIR, BATCH), dim3(256), 0, stream>>>(fb, fbT, sq, temp, Sp, Tp);
    finalize_kernel<<<dim3(BN / 4), dim3(256), 0, stream>>>(feat, Sp, Tp, tgt, temp, out);
}

// Round 13
// 165.250 us; speedup vs baseline: 1.0791x; 1.0791x over previous
//
#include <hip/hip_runtime.h>
#include <stdint.h>

#define N_TOK 4096
#define DIM   512
#define BATCH 4
#define BN    (BATCH * N_TOK)
#define JSPLIT 8
#define IPW   64                      // i-rows per wave (A resident in regs)
#define IPB   256                     // i-rows per block (4 waves)
#define NG    (N_TOK / JSPLIT / 16)   // 32 j-groups of 16 per slice

typedef __attribute__((ext_vector_type(4))) float f32x4;

__device__ __forceinline__ float sumsq8(uint lo, uint hi) {
    float s = 0.f, f;
    f = __builtin_amdgcn_cvt_f32_fp8((int)lo, 0); s = fmaf(f, f, s);
    f = __builtin_amdgcn_cvt_f32_fp8((int)lo, 1); s = fmaf(f, f, s);
    f = __builtin_amdgcn_cvt_f32_fp8((int)lo, 2); s = fmaf(f, f, s);
    f = __builtin_amdgcn_cvt_f32_fp8((int)lo, 3); s = fmaf(f, f, s);
    f = __builtin_amdgcn_cvt_f32_fp8((int)hi, 0); s = fmaf(f, f, s);
    f = __builtin_amdgcn_cvt_f32_fp8((int)hi, 1); s = fmaf(f, f, s);
    f = __builtin_amdgcn_cvt_f32_fp8((int)hi, 2); s = fmaf(f, f, s);
    f = __builtin_amdgcn_cvt_f32_fp8((int)hi, 3); s = fmaf(f, f, s);
    return s;
}

// ---------- prep: fp8 convert -> fb (row-major) + fbT (B-operand, 16B-load layout)
//            + per-row sumsq of QUANTIZED values (diag d_ii ~ 0 matches ref k_ii=1).
__global__ __launch_bounds__(256) void prep_kernel(
    const float* __restrict__ feat, uint8_t* __restrict__ fb,
    uint8_t* __restrict__ fbT, float* __restrict__ sq)
{
    __shared__ __align__(16) long lt[1024];        // [chunk c 0..63][row16], swizzled
    const int t = threadIdx.x;
    const int row16 = t >> 4, seg = t & 15;
    const size_t grp = blockIdx.x;
    const size_t row = grp * 16 + row16;

    const float4* src = (const float4*)(feat + row * DIM + seg * 32);
    uint32_t wd[8];
    float s = 0.f;
#pragma unroll
    for (int i = 0; i < 4; ++i) {
        float4 a = src[2 * i], b = src[2 * i + 1];
        uint lo = (uint)__builtin_amdgcn_cvt_pk_fp8_f32(a.x, a.y, 0, false);
        lo      = (uint)__builtin_amdgcn_cvt_pk_fp8_f32(a.z, a.w, (int)lo, true);
        uint hi = (uint)__builtin_amdgcn_cvt_pk_fp8_f32(b.x, b.y, 0, false);
        hi      = (uint)__builtin_amdgcn_cvt_pk_fp8_f32(b.z, b.w, (int)hi, true);
        wd[2 * i] = lo; wd[2 * i + 1] = hi;
        s += sumsq8(lo, hi);
    }

    uint4* dst = (uint4*)(fb + row * DIM + seg * 32);
    uint4 o0; o0.x = wd[0]; o0.y = wd[1]; o0.z = wd[2]; o0.w = wd[3];
    uint4 o1; o1.x = wd[4]; o1.y = wd[5]; o1.z = wd[6]; o1.w = wd[7];
    dst[0] = o0; dst[1] = o1;

#pragma unroll
    for (int i = 0; i < 4; ++i) {
        int c = seg * 4 + i;                       // 8B chunk of this row
        long d = ((long)(unsigned)wd[2 * i + 1] << 32) | (unsigned)wd[2 * i];
        lt[c * 16 + ((row16 + c) & 15)] = d;
    }

#pragma unroll
    for (int m = 1; m < 16; m <<= 1) s += __shfl_xor(s, m);
    if (seg == 0) sq[row] = s;

    __syncthreads();
    long* ot = (long*)(fbT + grp * 8192);
#pragma unroll
    for (int i = 0; i < 4; ++i) {
        int p    = t + i * 256;                    // output long index, coalesced
        int kp   = p >> 7;
        int q    = (p >> 5) & 3;
        int r    = (p >> 1) & 15;
        int half = p & 1;
        int c    = (((kp << 1) | half) << 2) | q;  // source chunk
        ot[p] = lt[c * 16 + ((r + c) & 15)];
    }
}

// ---------- entropy: R10 structure + software-pipelined B-loads ----------
// Flat 512-block grid (2/CU), XCD-swizzled (combo = flat&31 => jh = XCD id).
// Rotation: while MFMAing half-0 of group g, load half-1; while MFMAing half-1,
// load group g+1's half-0 => loads lead use by ~16 MFMA issues (~310cyc), covering
// L2 latency that the old structure exposed at every group boundary (the exp-skip
// branch blocked compiler load hoisting). Register peak unchanged (~244/wave).
__global__ __launch_bounds__(256, 2) void entropy_kernel(
    const uint8_t* __restrict__ fb, const uint8_t* __restrict__ fbT,
    const float* __restrict__ sq, const float* __restrict__ temp,
    float* __restrict__ Sp, float* __restrict__ Tp)
{
    const int t    = threadIdx.x;
    const int w    = t >> 6;
    const int lane = t & 63;
    const int q    = lane >> 4;
    const int c16  = lane & 15;

    const int flat  = blockIdx.x;
    const int combo = flat & 31;
    const int batch = combo >> 3;
    const int jh    = combo & 7;
    const int iblk  = flat >> 5;
    const int iw    = iblk * IPB + w * IPW;
    const size_t rowbase = (size_t)batch * N_TOK;

    const float tau    = temp[0];
    const float inv2t2 = 0.5f / (tau * tau);
    const float cg     = 1.0f / (tau * tau);

    // A fragments: 4 strips x 16 k-chunks x 8B = 128 regs
    long afrag[4][16];
#pragma unroll
    for (int s = 0; s < 4; ++s) {
        const long* ap = (const long*)(fb + (rowbase + iw + s * 16 + c16) * DIM);
#pragma unroll
        for (int kc = 0; kc < 16; ++kc) afrag[s][kc] = ap[kc * 4 + q];
    }
    float pi[4][4];
#pragma unroll
    for (int s = 0; s < 4; ++s)
#pragma unroll
        for (int r = 0; r < 4; ++r)
            pi[s][r] = -sq[rowbase + iw + s * 16 + q * 4 + r] * inv2t2;

    float S[4][4], T[4][4];
#pragma unroll
    for (int s = 0; s < 4; ++s)
#pragma unroll
        for (int r = 0; r < 4; ++r) { S[s][r] = 0.f; T[s][r] = 0.f; }

    // per-lane B pointer: 16B units; group stride 512 units, kp stride 64 units
    const longlong2* bp = (const longlong2*)(fbT
                        + ((size_t)batch * (N_TOK / 16) + (size_t)jh * NG) * 8192) + lane;
    const float* sqj = sq + rowbase + jh * (N_TOK / JSPLIT) + c16;

    longlong2 cur[4];                              // half-0 of group 0, preloaded
    {
        const longlong2* bg0 = bp;
#pragma unroll
        for (int i = 0; i < 4; ++i) cur[i] = bg0[i * 64];
    }

    for (int g = 0; g < NG; ++g) {
        const longlong2* bg  = bp + (size_t)g * 512;
        const longlong2* bgn = bp + (size_t)(g + 1 < NG ? g + 1 : g) * 512;
        float pj = -sqj[g * 16] * inv2t2;
        f32x4 acc[4] = {{0,0,0,0},{0,0,0,0},{0,0,0,0},{0,0,0,0}};

        longlong2 nxt[4];
#pragma unroll
        for (int i = 0; i < 4; ++i) {              // MFMA half-0, load half-1
            nxt[i] = bg[(4 + i) * 64];
            acc[0] = __builtin_amdgcn_mfma_f32_16x16x32_fp8_fp8(afrag[0][2*i],   cur[i].x, acc[0], 0, 0, 0);
            acc[1] = __builtin_amdgcn_mfma_f32_16x16x32_fp8_fp8(afrag[1][2*i],   cur[i].x, acc[1], 0, 0, 0);
            acc[2] = __builtin_amdgcn_mfma_f32_16x16x32_fp8_fp8(afrag[2][2*i],   cur[i].x, acc[2], 0, 0, 0);
            acc[3] = __builtin_amdgcn_mfma_f32_16x16x32_fp8_fp8(afrag[3][2*i],   cur[i].x, acc[3], 0, 0, 0);
            acc[0] = __builtin_amdgcn_mfma_f32_16x16x32_fp8_fp8(afrag[0][2*i+1], cur[i].y, acc[0], 0, 0, 0);
            acc[1] = __builtin_amdgcn_mfma_f32_16x16x32_fp8_fp8(afrag[1][2*i+1], cur[i].y, acc[1], 0, 0, 0);
            acc[2] = __builtin_amdgcn_mfma_f32_16x16x32_fp8_fp8(afrag[2][2*i+1], cur[i].y, acc[2], 0, 0, 0);
            acc[3] = __builtin_amdgcn_mfma_f32_16x16x32_fp8_fp8(afrag[3][2*i+1], cur[i].y, acc[3], 0, 0, 0);
        }
#pragma unroll
        for (int i = 0; i < 4; ++i) {              // MFMA half-1, load next half-0
            cur[i] = bgn[i * 64];
            int kc = 2 * (4 + i);
            acc[0] = __builtin_amdgcn_mfma_f32_16x16x32_fp8_fp8(afrag[0][kc],   nxt[i].x, acc[0], 0, 0, 0);
            acc[1] = __builtin_amdgcn_mfma_f32_16x16x32_fp8_fp8(afrag[1][kc],   nxt[i].x, acc[1], 0, 0, 0);
            acc[2] = __builtin_amdgcn_mfma_f32_16x16x32_fp8_fp8(afrag[2][kc],   nxt[i].x, acc[2], 0, 0, 0);
            acc[3] = __builtin_amdgcn_mfma_f32_16x16x32_fp8_fp8(afrag[3][kc],   nxt[i].x, acc[3], 0, 0, 0);
            acc[0] = __builtin_amdgcn_mfma_f32_16x16x32_fp8_fp8(afrag[0][kc+1], nxt[i].y, acc[0], 0, 0, 0);
            acc[1] = __builtin_amdgcn_mfma_f32_16x16x32_fp8_fp8(afrag[1][kc+1], nxt[i].y, acc[1], 0, 0, 0);
            acc[2] = __builtin_amdgcn_mfma_f32_16x16x32_fp8_fp8(afrag[2][kc+1], nxt[i].y, acc[2], 0, 0, 0);
            acc[3] = __builtin_amdgcn_mfma_f32_16x16x32_fp8_fp8(afrag[3][kc+1], nxt[i].y, acc[3], 0, 0, 0);
        }

        float m = -1e30f;
#pragma unroll
        for (int s = 0; s < 4; ++s)
#pragma unroll
            for (int r = 0; r < 4; ++r) {          // e in place of acc (dead after)
                acc[s][r] = fmaf(acc[s][r], cg, pi[s][r] + pj);
                m = fmaxf(m, acc[s][r]);
            }
        if (m > -110.0f) {                         // only diagonal-adjacent groups
#pragma unroll
            for (int s = 0; s < 4; ++s)
#pragma unroll
                for (int r = 0; r < 4; ++r) {
                    float ee = fminf(acc[s][r], 0.f);
                    float k  = __expf(ee);
                    S[s][r] += k;
                    T[s][r]  = fmaf(k, ee, T[s][r]);
                }
        }
    }

    // reduce over the 16 j-columns (c16 lanes)
#pragma unroll
    for (int m = 1; m < 16; m <<= 1)
#pragma unroll
        for (int s = 0; s < 4; ++s)
#pragma unroll
            for (int r = 0; r < 4; ++r) {
                S[s][r] += __shfl_xor(S[s][r], m);
                T[s][r] += __shfl_xor(T[s][r], m);
            }

    if (c16 == 0) {
#pragma unroll
        for (int s = 0; s < 4; ++s)
#pragma unroll
            for (int r = 0; r < 4; ++r) {
                size_t idx = (size_t)jh * BN + rowbase + iw + s * 16 + q * 4 + r;
                Sp[idx] = S[s][r];
                Tp[idx] = T[s][r];
            }
    }
}

// ---------- finalize: combine partials, entropy -> sigmoid -> scale features ----------
__global__ __launch_bounds__(256) void finalize_kernel(
    const float* __restrict__ feat, const float* __restrict__ Sp,
    const float* __restrict__ Tp, const float* __restrict__ tgt,
    const float* __restrict__ temp, float* __restrict__ out)
{
    int row  = (blockIdx.x << 2) + (threadIdx.x >> 6);   // global row 0..BN-1
    int lane = threadIdx.x & 63;
    float S = 0.0f, T = 0.0f;
#pragma unroll
    for (int j = 0; j < JSPLIT; ++j) {
        S += Sp[(size_t)j * BN + row];
        T += Tp[(size_t)j * BN + row];
    }
    float tau = temp[0];
    float E  = __logf(S) - T / S;                  // entropy (sans +1e-6, bias<4e-3)
    float cs = 1.0f / (1.0f + __expf((E - tgt[0]) / tau));

    const float4* F4 = (const float4*)(feat + (size_t)row * DIM);
    float4*       O4 = (float4*)(out + (size_t)row * DIM);
    float4 v0 = F4[lane], v1 = F4[lane + 64];
    v0.x *= cs; v0.y *= cs; v0.z *= cs; v0.w *= cs;
    v1.x *= cs; v1.y *= cs; v1.z *= cs; v1.w *= cs;
    O4[lane] = v0; O4[lane + 64] = v1;
    if (lane == 0) out[(size_t)BN * DIM + row] = cs;
}

extern "C" void kernel_launch(void* const* d_in, const int* in_sizes, int n_in,
                              void* d_out, int out_size, void* d_ws, size_t ws_size,
                              hipStream_t stream) {
    const float* feat = (const float*)d_in[0];
    const float* tgt  = (const float*)d_in[7];   // target_entropy
    const float* temp = (const float*)d_in[8];   // temperature
    float* out = (float*)d_out;

    char* ws = (char*)d_ws;
    uint8_t* fb  = (uint8_t*)ws;                               // fp8 row-major, 8.4MB
    uint8_t* fbT = fb + (size_t)BN * DIM;                      // fp8 B-layout, 8.4MB
    float*   sq  = (float*)(fbT + (size_t)BN * DIM);           // quantized row sumsq
    float*   Sp  = sq + BN;                                    // partial S, JSPLIT slices
    float*   Tp  = Sp + (size_t)JSPLIT * BN;                   // partial T, JSPLIT slices

    prep_kernel<<<dim3(BN / 16), dim3(256), 0, stream>>>(feat, fb, fbT, sq);
    entropy_kernel<<<dim3((N_TOK / IPB) * BATCH * JSPLIT), dim3(256), 0, stream>>>(fb, fbT, sq, temp, Sp, Tp);
    finalize_kernel<<<dim3(BN / 4), dim3(256), 0, stream>>>(feat, Sp, Tp, tgt, temp, out);
}

// Round 14
// 159.888 us; speedup vs baseline: 1.1153x; 1.0335x over previous
//
#include <hip/hip_runtime.h>
#include <stdint.h>

#define N_TOK 4096
#define DIM   512
#define BATCH 4
#define BN    (BATCH * N_TOK)
#define JSPLIT 8
#define IPW   64                      // i-rows per wave (A resident in regs)
#define IPB   256                     // i-rows per block (4 waves)
#define NG    (N_TOK / JSPLIT / 16)   // 32 j-groups of 16 per slice

typedef __attribute__((ext_vector_type(4))) float f32x4;
typedef __attribute__((ext_vector_type(8))) int   i32x8;

__device__ __forceinline__ float sumsq8(uint lo, uint hi) {
    float s = 0.f, f;
    f = __builtin_amdgcn_cvt_f32_fp8((int)lo, 0); s = fmaf(f, f, s);
    f = __builtin_amdgcn_cvt_f32_fp8((int)lo, 1); s = fmaf(f, f, s);
    f = __builtin_amdgcn_cvt_f32_fp8((int)lo, 2); s = fmaf(f, f, s);
    f = __builtin_amdgcn_cvt_f32_fp8((int)lo, 3); s = fmaf(f, f, s);
    f = __builtin_amdgcn_cvt_f32_fp8((int)hi, 0); s = fmaf(f, f, s);
    f = __builtin_amdgcn_cvt_f32_fp8((int)hi, 1); s = fmaf(f, f, s);
    f = __builtin_amdgcn_cvt_f32_fp8((int)hi, 2); s = fmaf(f, f, s);
    f = __builtin_amdgcn_cvt_f32_fp8((int)hi, 3); s = fmaf(f, f, s);
    return s;
}

// ---------- prep: fp8 convert -> fb (row-major) + fbT (B-operand, MX K=128 layout)
//            + per-row sumsq of QUANTIZED values (diag d_ii ~ 0 matches ref k_ii=1).
// fbT per 16-row group (8KB): byte offset = kk*2048 + q*512 + r16*32  (kk = which
// 128-wide K chunk, q = lane quad's 32-elem scale block, r16 = j row) => each lane's
// 32B B operand is 2 contiguous 16B loads; wave load is fully coalesced.
__global__ __launch_bounds__(256) void prep_kernel(
    const float* __restrict__ feat, uint8_t* __restrict__ fb,
    uint8_t* __restrict__ fbT, float* __restrict__ sq)
{
    __shared__ __align__(16) long lt[1024];        // [chunk c 0..63][row16], swizzled
    const int t = threadIdx.x;
    const int row16 = t >> 4, seg = t & 15;
    const size_t grp = blockIdx.x;
    const size_t row = grp * 16 + row16;

    const float4* src = (const float4*)(feat + row * DIM + seg * 32);
    uint32_t wd[8];
    float s = 0.f;
#pragma unroll
    for (int i = 0; i < 4; ++i) {
        float4 a = src[2 * i], b = src[2 * i + 1];
        uint lo = (uint)__builtin_amdgcn_cvt_pk_fp8_f32(a.x, a.y, 0, false);
        lo      = (uint)__builtin_amdgcn_cvt_pk_fp8_f32(a.z, a.w, (int)lo, true);
        uint hi = (uint)__builtin_amdgcn_cvt_pk_fp8_f32(b.x, b.y, 0, false);
        hi      = (uint)__builtin_amdgcn_cvt_pk_fp8_f32(b.z, b.w, (int)hi, true);
        wd[2 * i] = lo; wd[2 * i + 1] = hi;
        s += sumsq8(lo, hi);
    }

    uint4* dst = (uint4*)(fb + row * DIM + seg * 32);
    uint4 o0; o0.x = wd[0]; o0.y = wd[1]; o0.z = wd[2]; o0.w = wd[3];
    uint4 o1; o1.x = wd[4]; o1.y = wd[5]; o1.z = wd[6]; o1.w = wd[7];
    dst[0] = o0; dst[1] = o1;

#pragma unroll
    for (int i = 0; i < 4; ++i) {
        int c = seg * 4 + i;                       // 8B chunk of this row
        long d = ((long)(unsigned)wd[2 * i + 1] << 32) | (unsigned)wd[2 * i];
        lt[c * 16 + ((row16 + c) & 15)] = d;
    }

#pragma unroll
    for (int m = 1; m < 16; m <<= 1) s += __shfl_xor(s, m);
    if (seg == 0) sq[row] = s;

    __syncthreads();
    long* ot = (long*)(fbT + grp * 8192);
#pragma unroll
    for (int i = 0; i < 4; ++i) {
        int p   = t + i * 256;                     // output long index, coalesced
        int kk  = p >> 8;                          // 128-wide K chunk
        int rem = p & 255;
        int q   = rem >> 6;                        // 32-elem scale block
        int r   = (rem >> 2) & 15;                 // j row in group
        int w8  = p & 3;                           // 8B word within lane's 32B
        int c   = kk * 16 + q * 4 + w8;            // source 8B chunk in row
        ot[p] = lt[c * 16 + ((r + c) & 15)];
    }
}

// ---------- entropy: MX-scaled fp8 MFMA (K=128, 2x rate), register A+B ----------
// Flat 512-block grid (2/CU), XCD-swizzled (combo = flat&31 => jh = XCD id).
// Unit scales (E8M0=127 -> x1.0): products bit-identical to non-scaled fp8 path.
// Per wave-group: 8 x 16B loads + 16 MFMAs (was 64) => MFMA issue ~460cyc vs 1260.
__global__ __launch_bounds__(256, 2) void entropy_kernel(
    const uint8_t* __restrict__ fb, const uint8_t* __restrict__ fbT,
    const float* __restrict__ sq, const float* __restrict__ temp,
    float* __restrict__ Sp, float* __restrict__ Tp)
{
    const int t    = threadIdx.x;
    const int w    = t >> 6;
    const int lane = t & 63;
    const int q    = lane >> 4;
    const int c16  = lane & 15;

    const int flat  = blockIdx.x;
    const int combo = flat & 31;
    const int batch = combo >> 3;
    const int jh    = combo & 7;
    const int iblk  = flat >> 5;
    const int iw    = iblk * IPB + w * IPW;
    const size_t rowbase = (size_t)batch * N_TOK;

    const float tau    = temp[0];
    const float inv2t2 = 0.5f / (tau * tau);
    const float cg     = 1.0f / (tau * tau);

    // A fragments: 4 strips x 4 K-chunks x 32B = 128 regs (same residency as R13)
    i32x8 afrag[4][4];
#pragma unroll
    for (int s = 0; s < 4; ++s) {
        const uint4* ap = (const uint4*)(fb + (rowbase + iw + s * 16 + c16) * DIM);
#pragma unroll
        for (int kk = 0; kk < 4; ++kk) {
            uint4 lo = ap[kk * 8 + q * 2];
            uint4 hi = ap[kk * 8 + q * 2 + 1];
            i32x8 v = {(int)lo.x, (int)lo.y, (int)lo.z, (int)lo.w,
                       (int)hi.x, (int)hi.y, (int)hi.z, (int)hi.w};
            afrag[s][kk] = v;
        }
    }
    float pi[4][4];
#pragma unroll
    for (int s = 0; s < 4; ++s)
#pragma unroll
        for (int r = 0; r < 4; ++r)
            pi[s][r] = -sq[rowbase + iw + s * 16 + q * 4 + r] * inv2t2;

    float S[4][4], T[4][4];
#pragma unroll
    for (int s = 0; s < 4; ++s)
#pragma unroll
        for (int r = 0; r < 4; ++r) { S[s][r] = 0.f; T[s][r] = 0.f; }

    // per-lane B pointer (uint4 units): group g at g*512; within: kk*128 + q*32 + c16*2
    const uint4* bp = (const uint4*)(fbT
                    + ((size_t)batch * (N_TOK / 16) + (size_t)jh * NG) * 8192)
                    + q * 32 + c16 * 2;
    const float* sqj = sq + rowbase + jh * (N_TOK / JSPLIT) + c16;

    for (int g = 0; g < NG; ++g) {
        float pj = -sqj[g * 16] * inv2t2;
        const uint4* bg = bp + (size_t)g * 512;
        f32x4 acc[4] = {{0,0,0,0},{0,0,0,0},{0,0,0,0},{0,0,0,0}};
#pragma unroll
        for (int kk = 0; kk < 4; kk += 2) {        // 2 B chunks in flight (32 regs)
            uint4 l0 = bg[kk * 128],       h0 = bg[kk * 128 + 1];
            uint4 l1 = bg[(kk+1) * 128],   h1 = bg[(kk+1) * 128 + 1];
            i32x8 b0 = {(int)l0.x, (int)l0.y, (int)l0.z, (int)l0.w,
                        (int)h0.x, (int)h0.y, (int)h0.z, (int)h0.w};
            i32x8 b1 = {(int)l1.x, (int)l1.y, (int)l1.z, (int)l1.w,
                        (int)h1.x, (int)h1.y, (int)h1.z, (int)h1.w};
            acc[0] = __builtin_amdgcn_mfma_scale_f32_16x16x128_f8f6f4(afrag[0][kk], b0, acc[0], 0, 0, 0, 127, 0, 127);
            acc[1] = __builtin_amdgcn_mfma_scale_f32_16x16x128_f8f6f4(afrag[1][kk], b0, acc[1], 0, 0, 0, 127, 0, 127);
            acc[2] = __builtin_amdgcn_mfma_scale_f32_16x16x128_f8f6f4(afrag[2][kk], b0, acc[2], 0, 0, 0, 127, 0, 127);
            acc[3] = __builtin_amdgcn_mfma_scale_f32_16x16x128_f8f6f4(afrag[3][kk], b0, acc[3], 0, 0, 0, 127, 0, 127);
            acc[0] = __builtin_amdgcn_mfma_scale_f32_16x16x128_f8f6f4(afrag[0][kk+1], b1, acc[0], 0, 0, 0, 127, 0, 127);
            acc[1] = __builtin_amdgcn_mfma_scale_f32_16x16x128_f8f6f4(afrag[1][kk+1], b1, acc[1], 0, 0, 0, 127, 0, 127);
            acc[2] = __builtin_amdgcn_mfma_scale_f32_16x16x128_f8f6f4(afrag[2][kk+1], b1, acc[2], 0, 0, 0, 127, 0, 127);
            acc[3] = __builtin_amdgcn_mfma_scale_f32_16x16x128_f8f6f4(afrag[3][kk+1], b1, acc[3], 0, 0, 0, 127, 0, 127);
        }
        float m = -1e30f;
#pragma unroll
        for (int s = 0; s < 4; ++s)
#pragma unroll
            for (int r = 0; r < 4; ++r) {          // e in place of acc (dead after)
                acc[s][r] = fmaf(acc[s][r], cg, pi[s][r] + pj);
                m = fmaxf(m, acc[s][r]);
            }
        if (m > -110.0f) {                         // only diagonal-adjacent groups
#pragma unroll
            for (int s = 0; s < 4; ++s)
#pragma unroll
                for (int r = 0; r < 4; ++r) {
                    float ee = fminf(acc[s][r], 0.f);
                    float k  = __expf(ee);
                    S[s][r] += k;
                    T[s][r]  = fmaf(k, ee, T[s][r]);
                }
        }
    }

    // reduce over the 16 j-columns (c16 lanes)
#pragma unroll
    for (int m = 1; m < 16; m <<= 1)
#pragma unroll
        for (int s = 0; s < 4; ++s)
#pragma unroll
            for (int r = 0; r < 4; ++r) {
                S[s][r] += __shfl_xor(S[s][r], m);
                T[s][r] += __shfl_xor(T[s][r], m);
            }

    if (c16 == 0) {
#pragma unroll
        for (int s = 0; s < 4; ++s)
#pragma unroll
            for (int r = 0; r < 4; ++r) {
                size_t idx = (size_t)jh * BN + rowbase + iw + s * 16 + q * 4 + r;
                Sp[idx] = S[s][r];
                Tp[idx] = T[s][r];
            }
    }
}

// ---------- finalize: combine partials, entropy -> sigmoid -> scale features ----------
__global__ __launch_bounds__(256) void finalize_kernel(
    const float* __restrict__ feat, const float* __restrict__ Sp,
    const float* __restrict__ Tp, const float* __restrict__ tgt,
    const float* __restrict__ temp, float* __restrict__ out)
{
    int row  = (blockIdx.x << 2) + (threadIdx.x >> 6);   // global row 0..BN-1
    int lane = threadIdx.x & 63;
    float S = 0.0f, T = 0.0f;
#pragma unroll
    for (int j = 0; j < JSPLIT; ++j) {
        S += Sp[(size_t)j * BN + row];
        T += Tp[(size_t)j * BN + row];
    }
    float tau = temp[0];
    float E  = __logf(S) - T / S;                  // entropy (sans +1e-6, bias<4e-3)
    float cs = 1.0f / (1.0f + __expf((E - tgt[0]) / tau));

    const float4* F4 = (const float4*)(feat + (size_t)row * DIM);
    float4*       O4 = (float4*)(out + (size_t)row * DIM);
    float4 v0 = F4[lane], v1 = F4[lane + 64];
    v0.x *= cs; v0.y *= cs; v0.z *= cs; v0.w *= cs;
    v1.x *= cs; v1.y *= cs; v1.z *= cs; v1.w *= cs;
    O4[lane] = v0; O4[lane + 64] = v1;
    if (lane == 0) out[(size_t)BN * DIM + row] = cs;
}

extern "C" void kernel_launch(void* const* d_in, const int* in_sizes, int n_in,
                              void* d_out, int out_size, void* d_ws, size_t ws_size,
                              hipStream_t stream) {
    const float* feat = (const float*)d_in[0];
    const float* tgt  = (const float*)d_in[7];   // target_entropy
    const float* temp = (const float*)d_in[8];   // temperature
    float* out = (float*)d_out;

    char* ws = (char*)d_ws;
    uint8_t* fb  = (uint8_t*)ws;                               // fp8 row-major, 8.4MB
    uint8_t* fbT = fb + (size_t)BN * DIM;                      // fp8 B-layout, 8.4MB
    float*   sq  = (float*)(fbT + (size_t)BN * DIM);           // quantized row sumsq
    float*   Sp  = sq + BN;                                    // partial S, JSPLIT slices
    float*   Tp  = Sp + (size_t)JSPLIT * BN;                   // partial T, JSPLIT slices

    prep_kernel<<<dim3(BN / 16), dim3(256), 0, stream>>>(feat, fb, fbT, sq);
    entropy_kernel<<<dim3((N_TOK / IPB) * BATCH * JSPLIT), dim3(256), 0, stream>>>(fb, fbT, sq, temp, Sp, Tp);
    finalize_kernel<<<dim3(BN / 4), dim3(256), 0, stream>>>(feat, Sp, Tp, tgt, temp, out);
}